// Round 1
// baseline (137.895 us; speedup 1.0000x reference)
//
#include <hip/hip_runtime.h>
#include <hip/hip_bf16.h>

// CTRNN fused kernel for MI355X (gfx950).
// B=8192, D=512, N=512, K=D+N=1024, 6 unfolds, dt=0.1, tau=1.
// state' = 0.9*state + 0.1*tanh(inputs@W_in + state@W_rec + bias)
//
// Strategy:
//  - prep kernel: WT[n][k] = bf16(W[k][n])  (1 MB in d_ws) so MFMA B-fragments
//    are 16B-contiguous per lane.
//  - fused kernel: 256 blocks x 512 threads; each block owns BM=32 rows for the
//    whole 6-unfold recurrence. proj (inputs@W_in+bias) and f32 state live in
//    registers at MFMA C-layout positions; bf16 state lives in LDS (XOR-swizzled)
//    as the A operand. Only W is re-read (from L2) each unfold.

#define BB 8192
#define DD 512
#define NN 512
#define KK 1024
#define BM 32
#define NTHREADS 512
#define NUNFOLD 6

using short8 = __attribute__((ext_vector_type(8))) short;
using f32x4  = __attribute__((ext_vector_type(4))) float;

__device__ __forceinline__ unsigned short f2bf(float f) {
    // round-to-nearest-even f32 -> bf16 (finite inputs only)
    unsigned int u = __float_as_uint(f);
    u += 0x7fffu + ((u >> 16) & 1u);
    return (unsigned short)(u >> 16);
}

__global__ void wt_transpose_cast(const float* __restrict__ W,
                                  unsigned short* __restrict__ WT) {
    __shared__ float tile[32][33];
    const int k0 = blockIdx.x * 32;
    const int n0 = blockIdx.y * 32;
    const int tx = threadIdx.x & 31;
    const int ty = threadIdx.x >> 5;  // 0..7
#pragma unroll
    for (int j = 0; j < 32; j += 8)
        tile[ty + j][tx] = W[(size_t)(k0 + ty + j) * NN + (n0 + tx)];
    __syncthreads();
#pragma unroll
    for (int j = 0; j < 32; j += 8)
        WT[(size_t)(n0 + ty + j) * KK + (k0 + tx)] = f2bf(tile[tx][ty + j]);
}

__global__ __launch_bounds__(NTHREADS, 2)
void ctrnn_fused(const float* __restrict__ inputs,
                 const float* __restrict__ state,
                 const float* __restrict__ bias,
                 const unsigned short* __restrict__ WT,
                 float* __restrict__ out) {
    // bf16 A-tile (inputs first, then state), [r][c], XOR-swizzled byte addr
    __shared__ __align__(16) char Alds[BM * DD * 2];  // 32 KB

    const int tid  = threadIdx.x;
    const int lane = tid & 63;
    const int wv   = tid >> 6;        // wave 0..7, owns cols [wv*64, wv*64+64)
    const int row0 = blockIdx.x * BM;
    const int l15  = lane & 15;
    const int l4   = lane >> 4;       // 0..3
    const int lane_k = l4 * 8;        // A/B fragment k-offset
    const int colbase = wv * 64 + l15;

    // A-fragment read from swizzled LDS: row = mt*16 + l15, k-chunk of 8 bf16
    auto lda = [&](int mt, int k) -> short8 {
        int r = mt * 16 + l15;
        int byte = (r * 1024 + k * 2) ^ ((r & 7) << 4);
        return *reinterpret_cast<const short8*>(&Alds[byte]);
    };
    // stage a 32x512 f32 tile into LDS as swizzled bf16 (8 float4 per thread)
    auto stage = [&](const float* __restrict__ src) {
        const float4* s4 = reinterpret_cast<const float4*>(src);
#pragma unroll
        for (int i = 0; i < 8; ++i) {
            int q  = tid + i * NTHREADS;  // 0..4095 = r*128 + c4
            int r  = q >> 7;
            int c4 = q & 127;
            float4 v = s4[q];
            uint2 p;
            p.x = (unsigned int)f2bf(v.x) | ((unsigned int)f2bf(v.y) << 16);
            p.y = (unsigned int)f2bf(v.z) | ((unsigned int)f2bf(v.w) << 16);
            int byte = (r * 1024 + c4 * 8) ^ ((r & 7) << 4);
            *reinterpret_cast<uint2*>(&Alds[byte]) = p;
        }
    };

    // ---------------- phase 1: proj = inputs @ W_in + bias ----------------
    stage(inputs + (size_t)row0 * DD);
    __syncthreads();

    f32x4 acc[2][4];
#pragma unroll
    for (int mt = 0; mt < 2; ++mt)
#pragma unroll
        for (int nt = 0; nt < 4; ++nt)
            acc[mt][nt] = f32x4{0.f, 0.f, 0.f, 0.f};

#pragma unroll 4
    for (int ks = 0; ks < 16; ++ks) {
        int k = ks * 32 + lane_k;
        short8 a0 = lda(0, k);
        short8 a1 = lda(1, k);
        short8 b[4];
#pragma unroll
        for (int nt = 0; nt < 4; ++nt)
            b[nt] = *reinterpret_cast<const short8*>(
                WT + (size_t)(colbase + nt * 16) * KK + k);
#pragma unroll
        for (int nt = 0; nt < 4; ++nt) {
            acc[0][nt] = __builtin_amdgcn_mfma_f32_16x16x32_bf16(a0, b[nt], acc[0][nt], 0, 0, 0);
            acc[1][nt] = __builtin_amdgcn_mfma_f32_16x16x32_bf16(a1, b[nt], acc[1][nt], 0, 0, 0);
        }
    }

    f32x4 proj[2][4];
#pragma unroll
    for (int nt = 0; nt < 4; ++nt) {
        float bv = bias[wv * 64 + nt * 16 + l15];
#pragma unroll
        for (int mt = 0; mt < 2; ++mt)
#pragma unroll
            for (int j = 0; j < 4; ++j)
                proj[mt][nt][j] = acc[mt][nt][j] + bv;
    }

    // ---------------- phase 2: load state (LDS bf16 + f32 regs) ----------------
    __syncthreads();  // proj GEMM reads done, safe to overwrite LDS
    stage(state + (size_t)row0 * NN);

    f32x4 sreg[2][4];  // f32 master state at C-layout positions
#pragma unroll
    for (int mt = 0; mt < 2; ++mt)
#pragma unroll
        for (int nt = 0; nt < 4; ++nt)
#pragma unroll
            for (int j = 0; j < 4; ++j)
                sreg[mt][nt][j] =
                    state[(size_t)(row0 + mt * 16 + l4 * 4 + j) * NN +
                          (wv * 64 + nt * 16 + l15)];
    __syncthreads();

    // ---------------- phase 3: 6 unfolds ----------------
    for (int u = 0; u < NUNFOLD; ++u) {
#pragma unroll
        for (int mt = 0; mt < 2; ++mt)
#pragma unroll
            for (int nt = 0; nt < 4; ++nt)
                acc[mt][nt] = f32x4{0.f, 0.f, 0.f, 0.f};

#pragma unroll 4
        for (int ks = 0; ks < 16; ++ks) {
            int k = ks * 32 + lane_k;
            short8 a0 = lda(0, k);
            short8 a1 = lda(1, k);
            short8 b[4];
#pragma unroll
            for (int nt = 0; nt < 4; ++nt)
                b[nt] = *reinterpret_cast<const short8*>(
                    WT + (size_t)(colbase + nt * 16) * KK + DD + k);
#pragma unroll
            for (int nt = 0; nt < 4; ++nt) {
                acc[0][nt] = __builtin_amdgcn_mfma_f32_16x16x32_bf16(a0, b[nt], acc[0][nt], 0, 0, 0);
                acc[1][nt] = __builtin_amdgcn_mfma_f32_16x16x32_bf16(a1, b[nt], acc[1][nt], 0, 0, 0);
            }
        }
        __syncthreads();  // all LDS reads of old state done

        // state update + write new bf16 state to LDS
#pragma unroll
        for (int mt = 0; mt < 2; ++mt)
#pragma unroll
            for (int nt = 0; nt < 4; ++nt)
#pragma unroll
                for (int j = 0; j < 4; ++j) {
                    float x = acc[mt][nt][j] + proj[mt][nt][j];
                    float t = 1.f - 2.f / (__expf(2.f * x) + 1.f);  // tanh(x)
                    float s = sreg[mt][nt][j] * 0.9f + 0.1f * t;
                    sreg[mt][nt][j] = s;
                    int r = mt * 16 + l4 * 4 + j;
                    int c = wv * 64 + nt * 16 + l15;
                    int byte = (r * 1024 + c * 2) ^ ((r & 7) << 4);
                    *reinterpret_cast<unsigned short*>(&Alds[byte]) = f2bf(s);
                }
        __syncthreads();  // new state visible before next unfold's reads
    }

    // ---------------- epilogue: out = (state, state) ----------------
#pragma unroll
    for (int mt = 0; mt < 2; ++mt)
#pragma unroll
        for (int nt = 0; nt < 4; ++nt)
#pragma unroll
            for (int j = 0; j < 4; ++j) {
                size_t r = (size_t)(row0 + mt * 16 + l4 * 4 + j);
                int c = wv * 64 + nt * 16 + l15;
                float s = sreg[mt][nt][j];
                out[r * NN + c] = s;
                out[(size_t)BB * NN + r * NN + c] = s;
            }
}

extern "C" void kernel_launch(void* const* d_in, const int* in_sizes, int n_in,
                              void* d_out, int out_size, void* d_ws, size_t ws_size,
                              hipStream_t stream) {
    const float* inputs = (const float*)d_in[0];
    const float* state  = (const float*)d_in[1];
    const float* W      = (const float*)d_in[2];   // (1024, 512) row-major
    const float* bias   = (const float*)d_in[3];   // (512,)
    float* out = (float*)d_out;                    // 2 * 8192*512 f32
    unsigned short* WT = (unsigned short*)d_ws;    // bf16 [512][1024] = 1 MB

    dim3 gT(KK / 32, NN / 32);
    wt_transpose_cast<<<gT, 256, 0, stream>>>(W, WT);
    ctrnn_fused<<<BB / BM, NTHREADS, 0, stream>>>(inputs, state, bias, WT, out);
}